// Round 2
// baseline (830.408 us; speedup 1.0000x reference)
//
#include <hip/hip_runtime.h>

// BinTokenizer: thresholds[i] = i/256 exactly (fp32), x*256 exact (pow2 scale)
// => token = (int)(clip(x, 1e-6f, 1.0f-1e-6f) * 256.0f). Pure streaming op.
// Traffic: 512 MiB fp32 in + 512 MiB int32 out = 1.074 GB -> ~170 us @ 6.3 TB/s.
//
// R1: 4 independent float4 loads per thread (64 B/thread) for memory-level
// parallelism; exact-cover grid (32768 blocks x 256 thr x 4 vec4) so the hot
// path is guard-free. VPT=4 chosen so each block moves 16 KiB in + 16 KiB out.

#define VPT 4  // float4 vectors per thread

__device__ __forceinline__ int tokenize1(float x) {
    x = fminf(fmaxf(x, 1e-6f), 1.0f - 1e-6f);
    return (int)(x * 256.0f);   // x in (0,1) -> trunc == floor, result in [0,255]
}

__device__ __forceinline__ int4 tokenize4(float4 v) {
    int4 t;
    t.x = tokenize1(v.x);
    t.y = tokenize1(v.y);
    t.z = tokenize1(v.z);
    t.w = tokenize1(v.w);
    return t;
}

__global__ __launch_bounds__(256) void BinTokenizer_90812788507001_kernel(
        const float4* __restrict__ in, int4* __restrict__ out, int n4) {
    const int base = blockIdx.x * (256 * VPT) + threadIdx.x;
    if (base + 256 * (VPT - 1) < n4) {
        // guard-free fat path: 4 independent loads issued back-to-back
        float4 v0 = in[base];
        float4 v1 = in[base + 256];
        float4 v2 = in[base + 512];
        float4 v3 = in[base + 768];
        out[base]       = tokenize4(v0);
        out[base + 256] = tokenize4(v1);
        out[base + 512] = tokenize4(v2);
        out[base + 768] = tokenize4(v3);
    } else {
        #pragma unroll
        for (int j = 0; j < VPT; ++j) {
            int i = base + 256 * j;
            if (i < n4) out[i] = tokenize4(in[i]);
        }
    }
}

extern "C" void kernel_launch(void* const* d_in, const int* in_sizes, int n_in,
                              void* d_out, int out_size, void* d_ws, size_t ws_size,
                              hipStream_t stream) {
    const float4* in = (const float4*)d_in[0];   // 64*4096*512 fp32
    int4* out = (int4*)d_out;                    // int32 tokens
    int n = in_sizes[0];
    int n4 = n >> 2;                              // multiple of 4 for this problem
    int per_block = 256 * VPT;
    int grid = (n4 + per_block - 1) / per_block;  // 32768 for the bench shape
    BinTokenizer_90812788507001_kernel<<<grid, 256, 0, stream>>>(in, out, n4);
}